// Round 1
// baseline (763.223 us; speedup 1.0000x reference)
//
#include <hip/hip_runtime.h>
#include <math.h>

#define B_ 4
#define NTOK 1537
#define NH 16
#define NROWS 6148      // B_*NTOK
#define RPAD 6272       // 49*128, padded rows
#define KDIM 1024

typedef __attribute__((ext_vector_type(8))) short short8;
typedef __attribute__((ext_vector_type(4))) float f32x4;
typedef __attribute__((ext_vector_type(4))) unsigned short ushort4v;
typedef __attribute__((ext_vector_type(4))) unsigned int uint4v;

__device__ __forceinline__ float bf2f(unsigned short u){
  unsigned int x = ((unsigned int)u) << 16;
  return __uint_as_float(x);
}
__device__ __forceinline__ unsigned short f2bf(float f){
  unsigned int x = __float_as_uint(f);
  x += 0x7fff + ((x >> 16) & 1);   // RNE
  return (unsigned short)(x >> 16);
}
__device__ __forceinline__ void gload_lds16(const void* g, void* l){
  __builtin_amdgcn_global_load_lds((const __attribute__((address_space(1))) unsigned int*)g,
                                   (__attribute__((address_space(3))) unsigned int*)l, 16, 0, 0);
}
__device__ __forceinline__ f32x4 mfma16(short8 a, short8 b, f32x4 c){
  return __builtin_amdgcn_mfma_f32_16x16x32_bf16(a, b, c, 0, 0, 0);
}

// ---------------- conversions ----------------
__global__ __launch_bounds__(256) void cvt_w_kernel(const float* __restrict__ src,
                                                    unsigned short* __restrict__ dst, int n){
  int i = (blockIdx.x*256 + threadIdx.x)*4;
  if (i >= n) return;
  f32x4 v = *(const f32x4*)(src + i);
  ushort4v o;
  #pragma unroll
  for (int j=0;j<4;j++) o[j] = f2bf(v[j]);
  *(ushort4v*)(dst + i) = o;
}

__global__ __launch_bounds__(256) void cvt_x_kernel(const float* __restrict__ x,
                                                    unsigned short* __restrict__ xb){
  size_t i = ((size_t)blockIdx.x*256 + threadIdx.x)*4;
  if (i >= (size_t)RPAD*KDIM) return;
  size_t row = i >> 10;
  ushort4v o;
  if (row < NROWS){
    f32x4 v = *(const f32x4*)(x + i);
    #pragma unroll
    for (int j=0;j<4;j++) o[j] = f2bf(v[j]);
  } else {
    o = (ushort4v)0;
  }
  *(ushort4v*)(xb + i) = o;
}

// ---------------- RoPE tables (pos 0..12, 32 freqs) ----------------
__global__ void rope_tables_kernel(float* __restrict__ ct, float* __restrict__ st){
  int i = threadIdx.x;
  if (i >= 13*32) return;
  int p = i >> 5, j = i & 31;
  float th = powf(10000.f, -(float)j * (1.f/32.f));
  float ang = (float)p * th;
  ct[i] = cosf(ang);
  st[i] = sinf(ang);
}

// ---------------- stable argsort -> pos table ----------------
__global__ __launch_bounds__(256) void argsort_kernel(const int* __restrict__ ids,
                                                      int* __restrict__ postab){
  __shared__ int vals[1536];
  int b = blockIdx.x;
  const int* src = ids + b*1536;
  for (int i=threadIdx.x; i<1536; i+=256) vals[i] = src[i];
  __syncthreads();
  for (int i=threadIdx.x; i<1536; i+=256){
    int v = vals[i];
    int rank = 0;
    for (int j=0;j<1536;j++){
      int u = vals[j];
      rank += (u < v) || (u == v && j < i);   // stable rank
    }
    postab[b*1536 + rank] = (i % 12) + 1;     // (p % V) + 1
  }
}

// ---------------- RoPE apply, in-place on bf16 qkv (q and k parts) ----------------
__global__ __launch_bounds__(256) void rope_kernel(unsigned short* __restrict__ qkv,
                                                   const int* __restrict__ postab,
                                                   const float* __restrict__ ct,
                                                   const float* __restrict__ st){
  int idx = blockIdx.x*256 + threadIdx.x;
  if (idx >= B_*NTOK*NH) return;
  int h = idx & 15;
  int bn = idx >> 4;
  int b = bn / NTOK;
  int n = bn - b*NTOK;
  unsigned short* rowp = qkv + (size_t)bn*3072;
  int pos = (n == 0) ? 0 : postab[b*1536 + (n-1)];
  const float* cr = ct + pos*32;
  const float* sr = st + pos*32;
  #pragma unroll
  for (int part=0; part<2; part++){
    unsigned short* p = rowp + part*1024 + h*64;
    uint4v vv[8];
    #pragma unroll
    for (int i=0;i<8;i++) vv[i] = ((const uint4v*)p)[i];
    unsigned short* tp = (unsigned short*)vv;
    unsigned short ov[64];
    if (n == 0){
      #pragma unroll
      for (int j=0;j<32;j++){ ov[j] = tp[2*j]; ov[32+j] = tp[2*j+1]; }
    } else {
      #pragma unroll
      for (int j=0;j<32;j++){
        float re = bf2f(tp[2*j]), im = bf2f(tp[2*j+1]);
        float c = cr[j], s = sr[j];
        ov[j]    = f2bf(re*c - im*s);
        ov[32+j] = f2bf(re*s + im*c);
      }
    }
    #pragma unroll
    for (int i=0;i<8;i++) ((uint4v*)p)[i] = ((const uint4v*)ov)[i];
  }
}

// ---------------- bf16 MFMA GEMM: out[r][c] = (sum_k A[r][k]*W[c][k] + bias[c]) * scale
__global__ __launch_bounds__(256) void gemm_kernel(const unsigned short* __restrict__ A, int lda,
    const unsigned short* __restrict__ W,
    const float* __restrict__ bias, float scale,
    unsigned short* __restrict__ outb, float* __restrict__ outf, int ldo, int mvalid)
{
  __shared__ alignas(16) unsigned short At[128][32];
  __shared__ alignas(16) unsigned short Bt[128][32];
  int t = threadIdx.x, w = t >> 6, lane = t & 63;
  int g = lane >> 4, l15 = lane & 15;
  int rowBase = blockIdx.x * 128, colBase = blockIdx.y * 128;
  int rb = (w >> 1) * 64, cb = (w & 1) * 64;
  f32x4 acc[4][4];
  #pragma unroll
  for (int m=0;m<4;m++)
    #pragma unroll
    for (int n=0;n<4;n++) acc[m][n] = 0.f;
  int srow = lane >> 2;            // 0..15
  int scol = (lane & 3) * 8;       // 0,8,16,24
  for (int kb = 0; kb < KDIM; kb += 32){
    __syncthreads();
    #pragma unroll
    for (int i=0;i<2;i++){
      int rr = i*64 + w*16 + srow;
      gload_lds16(A + (size_t)(rowBase + rr)*lda + kb + scol, &At[i*64 + w*16][0]);
      gload_lds16(W + (size_t)(colBase + rr)*KDIM + kb + scol, &Bt[i*64 + w*16][0]);
    }
    __syncthreads();
    short8 af[4], bf[4];
    #pragma unroll
    for (int m=0;m<4;m++) af[m] = *(const short8*)&At[rb + m*16 + l15][g*8];
    #pragma unroll
    for (int n=0;n<4;n++) bf[n] = *(const short8*)&Bt[cb + n*16 + l15][g*8];
    #pragma unroll
    for (int m=0;m<4;m++)
      #pragma unroll
      for (int n=0;n<4;n++)
        acc[m][n] = mfma16(af[m], bf[n], acc[m][n]);
  }
  #pragma unroll
  for (int m=0;m<4;m++)
    #pragma unroll
    for (int n=0;n<4;n++){
      int col = colBase + cb + n*16 + l15;
      float bv = bias ? bias[col] : 0.f;
      #pragma unroll
      for (int r=0;r<4;r++){
        int row = rowBase + rb + m*16 + g*4 + r;
        if (row < mvalid){
          float v = (acc[m][n][r] + bv) * scale;
          if (outf) outf[(size_t)row*ldo + col] = v;
          else      outb[(size_t)row*ldo + col] = f2bf(v);
        }
      }
    }
}

// ---------------- flash attention ----------------
// grid (B*H, ceil(N/64)); 4 waves, each wave owns 16 q rows.
__global__ __launch_bounds__(256) void attn_kernel(const unsigned short* __restrict__ qp,
    const unsigned short* __restrict__ kp, const unsigned short* __restrict__ vp,
    unsigned short* __restrict__ ctx)
{
  __shared__ alignas(16) unsigned short Vlds[32][64];
  __shared__ alignas(16) unsigned short Plds[4][16][32];
  int bh = blockIdx.x;
  int qt = blockIdx.y;
  int b = bh >> 4, h = bh & 15;
  int t = threadIdx.x, w = t >> 6, lane = t & 63;
  int g = lane >> 4, l15 = lane & 15;
  int qrow = qt*64 + w*16 + l15;
  if (qrow > NTOK-1) qrow = NTOK-1;
  const unsigned short* qb = qp + (((size_t)(b*NTOK + qrow)*NH + h) << 6);
  short8 qf[2];
  qf[0] = *(const short8*)(qb + g*8);
  qf[1] = *(const short8*)(qb + 32 + g*8);
  float m_[4], l_[4];
  f32x4 o_[4];
  #pragma unroll
  for (int r=0;r<4;r++){ m_[r] = -3e38f; l_[r] = 0.f; }
  #pragma unroll
  for (int d=0;d<4;d++) o_[d] = 0.f;
  const int nkt = (NTOK + 31)/32;   // 49
  for (int kt=0; kt<nkt; ++kt){
    __syncthreads();
    {
      int key = kt*32 + (t >> 3);
      if (key > NTOK-1) key = NTOK-1;
      const unsigned short* vg = vp + (((size_t)(b*NTOK + key)*NH + h) << 6) + (t & 7)*8;
      gload_lds16(vg, &Vlds[w*8][0]);
    }
    __syncthreads();
    f32x4 c0 = 0.f, c1 = 0.f;
    int key0 = kt*32 + l15;
    int kl0 = key0      > NTOK-1 ? NTOK-1 : key0;
    int kl1 = key0 + 16 > NTOK-1 ? NTOK-1 : key0 + 16;
    const unsigned short* kb0 = kp + (((size_t)(b*NTOK + kl0)*NH + h) << 6) + g*8;
    const unsigned short* kb1 = kp + (((size_t)(b*NTOK + kl1)*NH + h) << 6) + g*8;
    #pragma unroll
    for (int kk=0;kk<2;kk++){
      short8 b0 = *(const short8*)(kb0 + kk*32);
      short8 b1 = *(const short8*)(kb1 + kk*32);
      c0 = mfma16(qf[kk], b0, c0);
      c1 = mfma16(qf[kk], b1, c1);
    }
    if (key0      >= NTOK) c0 = -1e30f;
    if (key0 + 16 >= NTOK) c1 = -1e30f;
    float mx[4], p0[4], p1[4], rs[4], al[4];
    #pragma unroll
    for (int r=0;r<4;r++) mx[r] = fmaxf(c0[r], c1[r]);
    #pragma unroll
    for (int s=1;s<16;s<<=1)
      #pragma unroll
      for (int r=0;r<4;r++) mx[r] = fmaxf(mx[r], __shfl_xor(mx[r], s));
    #pragma unroll
    for (int r=0;r<4;r++){
      float mn = fmaxf(m_[r], mx[r]);
      al[r] = __expf(m_[r] - mn);
      m_[r] = mn;
      p0[r] = __expf(c0[r] - mn);
      p1[r] = __expf(c1[r] - mn);
      rs[r] = p0[r] + p1[r];
    }
    #pragma unroll
    for (int s=1;s<16;s<<=1)
      #pragma unroll
      for (int r=0;r<4;r++) rs[r] += __shfl_xor(rs[r], s);
    #pragma unroll
    for (int r=0;r<4;r++) l_[r] = l_[r]*al[r] + rs[r];
    #pragma unroll
    for (int d=0;d<4;d++)
      #pragma unroll
      for (int r=0;r<4;r++) o_[d][r] *= al[r];
    #pragma unroll
    for (int r=0;r<4;r++){
      Plds[w][g*4+r][l15]      = f2bf(p0[r]);
      Plds[w][g*4+r][16 + l15] = f2bf(p1[r]);
    }
    asm volatile("s_waitcnt lgkmcnt(0)" ::: "memory");   // wave-sync LDS (cross-lane, same wave)
    short8 pf = *(const short8*)&Plds[w][l15][g*8];
    #pragma unroll
    for (int d=0;d<4;d++){
      short8 vf;
      #pragma unroll
      for (int i=0;i<8;i++) vf[i] = (short)Vlds[g*8+i][d*16 + l15];
      o_[d] = mfma16(pf, vf, o_[d]);
    }
  }
  float inv[4];
  #pragma unroll
  for (int r=0;r<4;r++) inv[r] = 1.f / l_[r];
  #pragma unroll
  for (int r=0;r<4;r++){
    int n = qt*64 + w*16 + g*4 + r;
    if (n < NTOK){
      unsigned short* cb = ctx + (((size_t)(b*NTOK + n)*NH + h) << 6);
      #pragma unroll
      for (int d=0;d<4;d++) cb[d*16 + l15] = f2bf(o_[d][r] * inv[r]);
    }
  }
}

extern "C" void kernel_launch(void* const* d_in, const int* in_sizes, int n_in,
                              void* d_out, int out_size, void* d_ws, size_t ws_size,
                              hipStream_t stream)
{
  const float* x    = (const float*)d_in[0];
  const float* qkvw = (const float*)d_in[1];
  const float* ipw  = (const float*)d_in[2];
  const float* ipb  = (const float*)d_in[3];
  const float* opw  = (const float*)d_in[4];
  const float* opb  = (const float*)d_in[5];
  const float* pw   = (const float*)d_in[6];
  const float* pb   = (const float*)d_in[7];
  const int*   ids  = (const int*)d_in[8];
  float* out = (float*)d_out;

  char* p = (char*)d_ws;
  auto alloc = [&](size_t bytes)->char* {
    char* r = p; p += (bytes + 255) & ~(size_t)255; return r;
  };
  unsigned short* xb    = (unsigned short*)alloc((size_t)RPAD*1024*2);
  unsigned short* qkvwb = (unsigned short*)alloc((size_t)3072*1024*2);
  unsigned short* ipwb  = (unsigned short*)alloc((size_t)3072*1024*2);
  unsigned short* opwb  = (unsigned short*)alloc((size_t)1024*1024*2);
  unsigned short* pwb   = (unsigned short*)alloc((size_t)1024*1024*2);
  unsigned short* qkvb  = (unsigned short*)alloc((size_t)RPAD*3072*2);
  unsigned short* qpb   = (unsigned short*)alloc((size_t)RPAD*1024*2);
  unsigned short* kpb   = (unsigned short*)alloc((size_t)RPAD*1024*2);
  unsigned short* vpb   = (unsigned short*)alloc((size_t)RPAD*1024*2);
  unsigned short* ctxb  = (unsigned short*)alloc((size_t)RPAD*1024*2);
  unsigned short* mhab  = (unsigned short*)alloc((size_t)RPAD*1024*2);
  int*   postab = (int*)alloc((size_t)B_*1536*4);
  float* ctab   = (float*)alloc(13*32*4);
  float* stab   = (float*)alloc(13*32*4);

  cvt_w_kernel<<<3072, 256, 0, stream>>>(qkvw, qkvwb, 3072*1024);
  cvt_w_kernel<<<3072, 256, 0, stream>>>(ipw,  ipwb,  3072*1024);
  cvt_w_kernel<<<1024, 256, 0, stream>>>(opw,  opwb,  1024*1024);
  cvt_w_kernel<<<1024, 256, 0, stream>>>(pw,   pwb,   1024*1024);
  cvt_x_kernel<<<RPAD, 256, 0, stream>>>(x, xb);   // RPAD*1024/(4*256) = RPAD blocks
  rope_tables_kernel<<<1, 512, 0, stream>>>(ctab, stab);
  argsort_kernel<<<B_, 256, 0, stream>>>(ids, postab);

  // qkv = x @ qkv_w^T  (no bias), bf16 out
  gemm_kernel<<<dim3(RPAD/128, 3072/128), 256, 0, stream>>>(xb, 1024, qkvwb, nullptr, 1.f,
                                                            qkvb, nullptr, 3072, NROWS);
  // RoPE in place on q,k
  rope_kernel<<<(B_*NTOK*NH + 255)/256, 256, 0, stream>>>(qkvb, postab, ctab, stab);
  // in_proj: qp (folded *0.125), kp, vp
  gemm_kernel<<<dim3(RPAD/128, 8), 256, 0, stream>>>(qkvb,        3072, ipwb,             ipb,      0.125f,
                                                     qpb, nullptr, 1024, NROWS);
  gemm_kernel<<<dim3(RPAD/128, 8), 256, 0, stream>>>(qkvb + 1024, 3072, ipwb + 1024*1024, ipb+1024, 1.f,
                                                     kpb, nullptr, 1024, NROWS);
  gemm_kernel<<<dim3(RPAD/128, 8), 256, 0, stream>>>(qkvb + 2048, 3072, ipwb + 2048*1024, ipb+2048, 1.f,
                                                     vpb, nullptr, 1024, NROWS);
  // attention
  attn_kernel<<<dim3(B_*NH, (NTOK+63)/64), 256, 0, stream>>>(qpb, kpb, vpb, ctxb);
  // out_proj then proj (final f32 to d_out)
  gemm_kernel<<<dim3(RPAD/128, 8), 256, 0, stream>>>(ctxb, 1024, opwb, opb, 1.f,
                                                     mhab, nullptr, 1024, NROWS);
  gemm_kernel<<<dim3(RPAD/128, 8), 256, 0, stream>>>(mhab, 1024, pwb,  pb,  1.f,
                                                     nullptr, out, 1024, NROWS);
}

// Round 2
// 572.274 us; speedup vs baseline: 1.3337x; 1.3337x over previous
//
#include <hip/hip_runtime.h>
#include <math.h>

#define B_ 4
#define NTOK 1537
#define NH 16
#define NROWS 6148      // B_*NTOK
#define RPAD 6272       // 49*128, padded rows
#define KDIM 1024
#define NKPAD 1568      // keys padded to 32-mult for aligned V^T loads

typedef __attribute__((ext_vector_type(8))) short short8;
typedef __attribute__((ext_vector_type(4))) float f32x4;
typedef __attribute__((ext_vector_type(4))) unsigned short ushort4v;
typedef __attribute__((ext_vector_type(4))) unsigned int uint4v;

__device__ __forceinline__ float bf2f(unsigned short u){
  unsigned int x = ((unsigned int)u) << 16;
  return __uint_as_float(x);
}
__device__ __forceinline__ unsigned short f2bf(float f){
  unsigned int x = __float_as_uint(f);
  x += 0x7fff + ((x >> 16) & 1);   // RNE
  return (unsigned short)(x >> 16);
}
__device__ __forceinline__ void gload_lds16(const void* g, void* l){
  __builtin_amdgcn_global_load_lds((const __attribute__((address_space(1))) unsigned int*)g,
                                   (__attribute__((address_space(3))) unsigned int*)l, 16, 0, 0);
}
__device__ __forceinline__ f32x4 mfma16(short8 a, short8 b, f32x4 c){
  return __builtin_amdgcn_mfma_f32_16x16x32_bf16(a, b, c, 0, 0, 0);
}

// ---------------- conversions ----------------
__global__ __launch_bounds__(256) void cvt_w_kernel(const float* __restrict__ src,
                                                    unsigned short* __restrict__ dst, int n){
  int i = (blockIdx.x*256 + threadIdx.x)*4;
  if (i >= n) return;
  f32x4 v = *(const f32x4*)(src + i);
  ushort4v o;
  #pragma unroll
  for (int j=0;j<4;j++) o[j] = f2bf(v[j]);
  *(ushort4v*)(dst + i) = o;
}

__global__ __launch_bounds__(256) void cvt_x_kernel(const float* __restrict__ x,
                                                    unsigned short* __restrict__ xb){
  size_t i = ((size_t)blockIdx.x*256 + threadIdx.x)*4;
  if (i >= (size_t)RPAD*KDIM) return;
  size_t row = i >> 10;
  ushort4v o;
  if (row < NROWS){
    f32x4 v = *(const f32x4*)(x + i);
    #pragma unroll
    for (int j=0;j<4;j++) o[j] = f2bf(v[j]);
  } else {
    o = (ushort4v)0;
  }
  *(ushort4v*)(xb + i) = o;
}

// ---------------- RoPE tables (pos 0..12, 32 freqs) ----------------
__global__ void rope_tables_kernel(float* __restrict__ ct, float* __restrict__ st){
  int i = threadIdx.x;
  if (i >= 13*32) return;
  int p = i >> 5, j = i & 31;
  float th = powf(10000.f, -(float)j * (1.f/32.f));
  float ang = (float)p * th;
  ct[i] = cosf(ang);
  st[i] = sinf(ang);
}

// ---------------- stable argsort -> pos table ----------------
// grid (B_, 6): each block ranks 256 elements of one batch.
__global__ __launch_bounds__(256) void argsort_kernel(const int* __restrict__ ids,
                                                      int* __restrict__ postab){
  __shared__ int vals[1536];
  int b = blockIdx.x;
  const int* src = ids + b*1536;
  for (int i=threadIdx.x; i<1536; i+=256) vals[i] = src[i];
  __syncthreads();
  int i = blockIdx.y*256 + threadIdx.x;
  int v = vals[i];
  int rank = 0;
  for (int j=0;j<1536;j++){
    int u = vals[j];
    rank += (u < v) || (u == v && j < i);   // stable rank
  }
  postab[b*1536 + rank] = (i % 12) + 1;     // (p % V) + 1
}

// ---------------- RoPE apply, in-place on bf16 qkv (q and k parts) ----------------
__global__ __launch_bounds__(256) void rope_kernel(unsigned short* __restrict__ qkv,
                                                   const int* __restrict__ postab,
                                                   const float* __restrict__ ct,
                                                   const float* __restrict__ st){
  int idx = blockIdx.x*256 + threadIdx.x;
  if (idx >= B_*NTOK*NH) return;
  int h = idx & 15;
  int bn = idx >> 4;
  int b = bn / NTOK;
  int n = bn - b*NTOK;
  unsigned short* rowp = qkv + (size_t)bn*3072;
  int pos = (n == 0) ? 0 : postab[b*1536 + (n-1)];
  const float* cr = ct + pos*32;
  const float* sr = st + pos*32;
  #pragma unroll
  for (int part=0; part<2; part++){
    unsigned short* p = rowp + part*1024 + h*64;
    uint4v vv[8];
    #pragma unroll
    for (int i=0;i<8;i++) vv[i] = ((const uint4v*)p)[i];
    unsigned short* tp = (unsigned short*)vv;
    unsigned short ov[64];
    if (n == 0){
      #pragma unroll
      for (int j=0;j<32;j++){ ov[j] = tp[2*j]; ov[32+j] = tp[2*j+1]; }
    } else {
      #pragma unroll
      for (int j=0;j<32;j++){
        float re = bf2f(tp[2*j]), im = bf2f(tp[2*j+1]);
        float c = cr[j], s = sr[j];
        ov[j]    = f2bf(re*c - im*s);
        ov[32+j] = f2bf(re*s + im*c);
      }
    }
    #pragma unroll
    for (int i=0;i<8;i++) ((uint4v*)p)[i] = ((const uint4v*)ov)[i];
  }
}

// ---------------- bf16 MFMA GEMM: out[r][c] = (sum_k A[r][k]*W[c][k] + bias[c]) * scale
__global__ __launch_bounds__(256) void gemm_kernel(const unsigned short* __restrict__ A, int lda,
    const unsigned short* __restrict__ W,
    const float* __restrict__ bias, float scale,
    unsigned short* __restrict__ outb, float* __restrict__ outf, int ldo, int mvalid)
{
  __shared__ alignas(16) unsigned short At[128][32];
  __shared__ alignas(16) unsigned short Bt[128][32];
  int t = threadIdx.x, w = t >> 6, lane = t & 63;
  int g = lane >> 4, l15 = lane & 15;
  int rowBase = blockIdx.x * 128, colBase = blockIdx.y * 128;
  int rb = (w >> 1) * 64, cb = (w & 1) * 64;
  f32x4 acc[4][4];
  #pragma unroll
  for (int m=0;m<4;m++)
    #pragma unroll
    for (int n=0;n<4;n++) acc[m][n] = 0.f;
  int srow = lane >> 2;            // 0..15
  int scol = (lane & 3) * 8;       // 0,8,16,24
  for (int kb = 0; kb < KDIM; kb += 32){
    __syncthreads();
    #pragma unroll
    for (int i=0;i<2;i++){
      int rr = i*64 + w*16 + srow;
      gload_lds16(A + (size_t)(rowBase + rr)*lda + kb + scol, &At[i*64 + w*16][0]);
      gload_lds16(W + (size_t)(colBase + rr)*KDIM + kb + scol, &Bt[i*64 + w*16][0]);
    }
    __syncthreads();
    short8 af[4], bf[4];
    #pragma unroll
    for (int m=0;m<4;m++) af[m] = *(const short8*)&At[rb + m*16 + l15][g*8];
    #pragma unroll
    for (int n=0;n<4;n++) bf[n] = *(const short8*)&Bt[cb + n*16 + l15][g*8];
    #pragma unroll
    for (int m=0;m<4;m++)
      #pragma unroll
      for (int n=0;n<4;n++)
        acc[m][n] = mfma16(af[m], bf[n], acc[m][n]);
  }
  #pragma unroll
  for (int m=0;m<4;m++)
    #pragma unroll
    for (int n=0;n<4;n++){
      int col = colBase + cb + n*16 + l15;
      float bv = bias ? bias[col] : 0.f;
      #pragma unroll
      for (int r=0;r<4;r++){
        int row = rowBase + rb + m*16 + g*4 + r;
        if (row < mvalid){
          float v = (acc[m][n][r] + bv) * scale;
          if (outf) outf[(size_t)row*ldo + col] = v;
          else      outb[(size_t)row*ldo + col] = f2bf(v);
        }
      }
    }
}

// ---------------- V transpose: vp[b*NTOK+n][h*64+e] -> vt[((b*16+h)*64+e)][NKPAD keys]
// grid (25, 16, 4), block 256. Zero-fills keys [NTOK, NKPAD).
__global__ __launch_bounds__(256) void vtrans_kernel(const unsigned short* __restrict__ vp,
                                                     unsigned short* __restrict__ vt){
  __shared__ alignas(16) unsigned short Tl[64][72];   // +8 u16 pad: 16B-aligned rows, spread banks
  int tile = blockIdx.x, head = blockIdx.y, b = blockIdx.z;
  int t = threadIdx.x;
  // load phase: r = t>>2 (token within tile), ch = t&3 (16-col chunk)
  {
    int r = t >> 2, ch = t & 3;
    int tok = tile*64 + r;
    uint4v v0, v1;
    if (tok < NTOK){
      const unsigned short* src = vp + (size_t)(b*NTOK + tok)*KDIM + head*64 + ch*16;
      v0 = *(const uint4v*)src;
      v1 = *(const uint4v*)(src + 8);
    } else { v0 = (uint4v)0; v1 = (uint4v)0; }
    *(uint4v*)&Tl[r][ch*16]     = v0;
    *(uint4v*)&Tl[r][ch*16 + 8] = v1;
  }
  __syncthreads();
  // store phase: c = t&63 (dim within head), rchunk = t>>6 (16-token chunk)
  {
    int c = t & 63, rchunk = t >> 6;
    int tokBase = tile*64 + rchunk*16;
    if (tokBase < NKPAD){
      unsigned short ov[16];
      #pragma unroll
      for (int j=0;j<16;j++) ov[j] = Tl[rchunk*16 + j][c];
      unsigned short* dst = vt + ((size_t)(((b*16 + head) << 6) + c))*NKPAD + tokBase;
      *(uint4v*)dst       = *(const uint4v*)&ov[0];
      *(uint4v*)(dst + 8) = *(const uint4v*)&ov[8];
    }
  }
}

// ---------------- flash attention ----------------
// grid (B*H, ceil(N/64)); 4 independent waves, each owns 16 q rows. No block-level sync.
__global__ __launch_bounds__(256) void attn_kernel(const unsigned short* __restrict__ qp,
    const unsigned short* __restrict__ kp, const unsigned short* __restrict__ vt,
    unsigned short* __restrict__ ctx)
{
  __shared__ alignas(16) unsigned short Plds[4][16][32];
  int bh = blockIdx.x;
  int qt = blockIdx.y;
  int b = bh >> 4, h = bh & 15;
  int t = threadIdx.x, w = t >> 6, lane = t & 63;
  int g = lane >> 4, l15 = lane & 15;
  int qrow = qt*64 + w*16 + l15;
  if (qrow > NTOK-1) qrow = NTOK-1;
  const unsigned short* qb = qp + (((size_t)(b*NTOK + qrow)*NH + h) << 6);
  short8 qf[2];
  qf[0] = *(const short8*)(qb + g*8);
  qf[1] = *(const short8*)(qb + 32 + g*8);
  // V^T: lane reads row (bh*64 + d*16 + l15), key column kt*32 + g*8 (+j)
  const unsigned short* vbase = vt + ((size_t)((bh << 6) + l15))*NKPAD;
  float m_[4], l_[4];
  f32x4 o_[4];
  #pragma unroll
  for (int r=0;r<4;r++){ m_[r] = -3e38f; l_[r] = 0.f; }
  #pragma unroll
  for (int d=0;d<4;d++) o_[d] = 0.f;
  const int nkt = (NTOK + 31)/32;   // 49
  for (int kt=0; kt<nkt; ++kt){
    f32x4 c0 = 0.f, c1 = 0.f;
    int key0 = kt*32 + l15;
    int kl0 = key0      > NTOK-1 ? NTOK-1 : key0;
    int kl1 = key0 + 16 > NTOK-1 ? NTOK-1 : key0 + 16;
    const unsigned short* kb0 = kp + (((size_t)(b*NTOK + kl0)*NH + h) << 6) + g*8;
    const unsigned short* kb1 = kp + (((size_t)(b*NTOK + kl1)*NH + h) << 6) + g*8;
    #pragma unroll
    for (int kk=0;kk<2;kk++){
      short8 b0 = *(const short8*)(kb0 + kk*32);
      short8 b1 = *(const short8*)(kb1 + kk*32);
      c0 = mfma16(qf[kk], b0, c0);
      c1 = mfma16(qf[kk], b1, c1);
    }
    if (key0      >= NTOK) c0 = -1e30f;
    if (key0 + 16 >= NTOK) c1 = -1e30f;
    float mx[4], p0[4], p1[4], rs[4], al[4];
    #pragma unroll
    for (int r=0;r<4;r++) mx[r] = fmaxf(c0[r], c1[r]);
    #pragma unroll
    for (int s=1;s<16;s<<=1)
      #pragma unroll
      for (int r=0;r<4;r++) mx[r] = fmaxf(mx[r], __shfl_xor(mx[r], s));
    #pragma unroll
    for (int r=0;r<4;r++){
      float mn = fmaxf(m_[r], mx[r]);
      al[r] = __expf(m_[r] - mn);
      m_[r] = mn;
      p0[r] = __expf(c0[r] - mn);
      p1[r] = __expf(c1[r] - mn);
      rs[r] = p0[r] + p1[r];
    }
    #pragma unroll
    for (int s=1;s<16;s<<=1)
      #pragma unroll
      for (int r=0;r<4;r++) rs[r] += __shfl_xor(rs[r], s);
    #pragma unroll
    for (int r=0;r<4;r++) l_[r] = l_[r]*al[r] + rs[r];
    #pragma unroll
    for (int d=0;d<4;d++)
      #pragma unroll
      for (int r=0;r<4;r++) o_[d][r] *= al[r];
    #pragma unroll
    for (int r=0;r<4;r++){
      Plds[w][g*4+r][l15]      = f2bf(p0[r]);
      Plds[w][g*4+r][16 + l15] = f2bf(p1[r]);
    }
    asm volatile("s_waitcnt lgkmcnt(0)" ::: "memory");   // wave-local LDS ordering
    short8 pf = *(const short8*)&Plds[w][l15][g*8];
    int kcol = kt*32 + g*8;
    #pragma unroll
    for (int d=0;d<4;d++){
      short8 vf = *(const short8*)(vbase + (size_t)(d*16)*NKPAD + kcol);
      o_[d] = mfma16(pf, vf, o_[d]);
    }
  }
  float inv[4];
  #pragma unroll
  for (int r=0;r<4;r++) inv[r] = 1.f / l_[r];
  #pragma unroll
  for (int r=0;r<4;r++){
    int n = qt*64 + w*16 + g*4 + r;
    if (n < NTOK){
      unsigned short* cb = ctx + (((size_t)(b*NTOK + n)*NH + h) << 6);
      #pragma unroll
      for (int d=0;d<4;d++) cb[d*16 + l15] = f2bf(o_[d][r] * inv[r]);
    }
  }
}

extern "C" void kernel_launch(void* const* d_in, const int* in_sizes, int n_in,
                              void* d_out, int out_size, void* d_ws, size_t ws_size,
                              hipStream_t stream)
{
  const float* x    = (const float*)d_in[0];
  const float* qkvw = (const float*)d_in[1];
  const float* ipw  = (const float*)d_in[2];
  const float* ipb  = (const float*)d_in[3];
  const float* opw  = (const float*)d_in[4];
  const float* opb  = (const float*)d_in[5];
  const float* pw   = (const float*)d_in[6];
  const float* pb   = (const float*)d_in[7];
  const int*   ids  = (const int*)d_in[8];
  float* out = (float*)d_out;

  char* p = (char*)d_ws;
  auto alloc = [&](size_t bytes)->char* {
    char* r = p; p += (bytes + 255) & ~(size_t)255; return r;
  };
  unsigned short* xb    = (unsigned short*)alloc((size_t)RPAD*1024*2);   // reused as vt after qkv GEMM
  unsigned short* qkvwb = (unsigned short*)alloc((size_t)3072*1024*2);
  unsigned short* ipwb  = (unsigned short*)alloc((size_t)3072*1024*2);
  unsigned short* opwb  = (unsigned short*)alloc((size_t)1024*1024*2);
  unsigned short* pwb   = (unsigned short*)alloc((size_t)1024*1024*2);
  unsigned short* qkvb  = (unsigned short*)alloc((size_t)RPAD*3072*2);
  unsigned short* qpb   = (unsigned short*)alloc((size_t)RPAD*1024*2);
  unsigned short* kpb   = (unsigned short*)alloc((size_t)RPAD*1024*2);
  unsigned short* vpb   = (unsigned short*)alloc((size_t)RPAD*1024*2);
  unsigned short* ctxb  = (unsigned short*)alloc((size_t)RPAD*1024*2);
  unsigned short* mhab  = (unsigned short*)alloc((size_t)RPAD*1024*2);
  int*   postab = (int*)alloc((size_t)B_*1536*4);
  float* ctab   = (float*)alloc(13*32*4);
  float* stab   = (float*)alloc(13*32*4);
  unsigned short* vtb = xb;   // alias: xb (RPAD*1024*2 = 12,845,056 B) == vt (4096*NKPAD*2 = 12,845,056 B)

  cvt_w_kernel<<<3072, 256, 0, stream>>>(qkvw, qkvwb, 3072*1024);
  cvt_w_kernel<<<3072, 256, 0, stream>>>(ipw,  ipwb,  3072*1024);
  cvt_w_kernel<<<1024, 256, 0, stream>>>(opw,  opwb,  1024*1024);
  cvt_w_kernel<<<1024, 256, 0, stream>>>(pw,   pwb,   1024*1024);
  cvt_x_kernel<<<RPAD, 256, 0, stream>>>(x, xb);
  rope_tables_kernel<<<1, 512, 0, stream>>>(ctab, stab);
  argsort_kernel<<<dim3(B_, 6), 256, 0, stream>>>(ids, postab);

  // qkv = x @ qkv_w^T  (no bias), bf16 out
  gemm_kernel<<<dim3(RPAD/128, 3072/128), 256, 0, stream>>>(xb, 1024, qkvwb, nullptr, 1.f,
                                                            qkvb, nullptr, 3072, NROWS);
  // RoPE in place on q,k
  rope_kernel<<<(B_*NTOK*NH + 255)/256, 256, 0, stream>>>(qkvb, postab, ctab, stab);
  // in_proj: qp (folded *0.125), kp, vp
  gemm_kernel<<<dim3(RPAD/128, 8), 256, 0, stream>>>(qkvb,        3072, ipwb,             ipb,      0.125f,
                                                     qpb, nullptr, 1024, NROWS);
  gemm_kernel<<<dim3(RPAD/128, 8), 256, 0, stream>>>(qkvb + 1024, 3072, ipwb + 1024*1024, ipb+1024, 1.f,
                                                     kpb, nullptr, 1024, NROWS);
  gemm_kernel<<<dim3(RPAD/128, 8), 256, 0, stream>>>(qkvb + 2048, 3072, ipwb + 2048*1024, ipb+2048, 1.f,
                                                     vpb, nullptr, 1024, NROWS);
  // V transpose into vt (aliases dead xb)
  vtrans_kernel<<<dim3(25, 16, 4), 256, 0, stream>>>(vpb, vtb);
  // attention
  attn_kernel<<<dim3(B_*NH, (NTOK+63)/64), 256, 0, stream>>>(qpb, kpb, vtb, ctxb);
  // out_proj then proj (final f32 to d_out)
  gemm_kernel<<<dim3(RPAD/128, 8), 256, 0, stream>>>(ctxb, 1024, opwb, opb, 1.f,
                                                     mhab, nullptr, 1024, NROWS);
  gemm_kernel<<<dim3(RPAD/128, 8), 256, 0, stream>>>(mhab, 1024, pwb,  pb,  1.f,
                                                     nullptr, out, 1024, NROWS);
}